// Round 18
// baseline (357.067 us; speedup 1.0000x reference)
//
#include <hip/hip_runtime.h>
#include <math.h>

// Problem constants (fixed by the reference)
constexpr int NN  = 50000;   // nodes
constexpr int NE  = 600000;  // edges
constexpr int D   = 128;     // DIM == HID
constexpr int IND = 392;     // 3*DIM + TEMB

constexpr int NB_NODE = (NN + 127) / 128;          // 391 node blocks
constexpr int NB_FILL = (NE + 511) / 512;          // 1172 fill blocks

typedef __attribute__((ext_vector_type(8))) short bf16x8;   // 8 bf16 = 4 VGPR
typedef __attribute__((ext_vector_type(4))) float f32x4;    // MFMA accumulator

__device__ __forceinline__ float4 ld4(const float* p) { return *reinterpret_cast<const float4*>(p); }

// float -> bf16 (RNE) and back
__device__ __forceinline__ unsigned short f2bf(float f) {
  unsigned int u = __float_as_uint(f);
  u += 0x7fffu + ((u >> 16) & 1u);
  return (unsigned short)(u >> 16);
}
__device__ __forceinline__ float bf2f(unsigned short s) {
  return __uint_as_float(((unsigned int)s) << 16);
}

// ---------------------------------------------------------------------------
// K0: merged pre-pass + histogram. Blocks 0..63: weight conversion.
// Blocks 64..: degree histogram.
// ---------------------------------------------------------------------------
__global__ __launch_bounds__(256) void k_preph(
    const float* __restrict__ ew1, const float* __restrict__ type_emb,
    const float* __restrict__ mw1, const float* __restrict__ mw2,
    const int* __restrict__ ei,
    unsigned short* __restrict__ Wab, unsigned short* __restrict__ Wbb,
    unsigned short* __restrict__ Wcb,
    unsigned short* __restrict__ m1b, unsigned short* __restrict__ m2b,
    float* __restrict__ tvg, int* __restrict__ deg)
{
  const int b = blockIdx.x, t = threadIdx.x;
  if (b < 64) {
    int g = b * 256 + t;   // 0..16383
    int o = g >> 7, k = g & 127;
    Wab[g] = f2bf(ew1[o * IND + k]);
    Wbb[g] = f2bf(ew1[o * IND + 128 + k]);
    Wcb[g] = f2bf(ew1[o * IND + 256 + k]);
    m1b[g] = f2bf(mw1[g]);
    m2b[g] = f2bf(mw2[g]);
    if (b == 0) {
      int oo = t & 127, ty = t >> 7;
      float s = 0.f;
#pragma unroll
      for (int j = 0; j < 8; ++j) s += ew1[oo * IND + 384 + j] * type_emb[ty * 8 + j];
      tvg[ty * 128 + oo] = s;
    }
  } else {
    int e = (b - 64) * 256 + t;
    if (e < NE) atomicAdd(&deg[ei[e]], 1);
  }
}

// ---------------------------------------------------------------------------
// 1-term MFMA micro-GEMM: acc[nt] += X-tile(rows me..me+15) . W^T  (K=128)
// ---------------------------------------------------------------------------
__device__ __forceinline__ void mm1(
    const unsigned short (*X)[136], const unsigned short (*W)[136],
    int me, int r, int q, f32x4 acc[8])
{
#pragma unroll
  for (int ks = 0; ks < 4; ++ks) {
    bf16x8 a = *reinterpret_cast<const bf16x8*>(&X[me + r][ks * 32 + q * 8]);
#pragma unroll
    for (int nt = 0; nt < 8; ++nt) {
      bf16x8 b = *reinterpret_cast<const bf16x8*>(&W[nt * 16 + r][ks * 32 + q * 8]);
      acc[nt] = __builtin_amdgcn_mfma_f32_16x16x32_bf16(a, b, acc[nt], 0, 0, 0);
    }
  }
}

// ---------------------------------------------------------------------------
// K1 v4: MERGED node-precompute + CSR fill.
// Blocks 0..NB_NODE-1: per-node MFMA precompute (512 thr, 8 waves, 69.6KB LDS).
// Blocks NB_NODE..  : CSR fill (atomic cursor scatter; LDS unused).
// ---------------------------------------------------------------------------
__global__ __launch_bounds__(512, 2) void k_nodefill(
    const float* __restrict__ z,
    const unsigned short* __restrict__ Wab, const unsigned short* __restrict__ Wbb,
    const unsigned short* __restrict__ m1b, const unsigned short* __restrict__ m2b,
    const float* __restrict__ mb1, const float* __restrict__ mb2,
    unsigned short* __restrict__ Ab, unsigned short* __restrict__ Bb,
    unsigned short* __restrict__ Mb, unsigned short* __restrict__ zb,
    const int* __restrict__ ei, int* __restrict__ cursor,
    int* __restrict__ eid, int* __restrict__ de_perm)
{
  __shared__ unsigned short Xh[128][136];
  __shared__ unsigned short Wh[128][136];
  const int t = threadIdx.x;

  if (blockIdx.x >= NB_NODE) {
    // ---------------- CSR fill part ----------------
    int e = (blockIdx.x - NB_NODE) * 512 + t;
    if (e < NE) {
      int pos = atomicAdd(&cursor[ei[e]], 1);
      eid[pos] = e;
      de_perm[pos] = ei[NE + e];
    }
    return;
  }

  // ---------------- node precompute part ----------------
  const int n0 = blockIdx.x * 128;

  // stage z (bf16) into Xh; also write zb
#pragma unroll
  for (int it = 0; it < 8; ++it) {
    int f = it * 512 + t, rr = f >> 5, c4 = (f & 31) * 4;
    int n = n0 + rr; if (n >= NN) n = NN - 1;
    float4 v = ld4(&z[(size_t)n * D + c4]);
    ushort4 hi;
    hi.x = f2bf(v.x); hi.y = f2bf(v.y); hi.z = f2bf(v.z); hi.w = f2bf(v.w);
    *reinterpret_cast<ushort4*>(&Xh[rr][c4]) = hi;
    if (n0 + rr < NN)
      *reinterpret_cast<ushort4*>(&zb[(size_t)(n0 + rr) * D + c4]) = hi;
  }
  // stage Wa
#pragma unroll
  for (int it = 0; it < 4; ++it) {
    int f = it * 512 + t, row = f >> 4, c8 = (f & 15) * 8;
    *reinterpret_cast<bf16x8*>(&Wh[row][c8]) =
        *reinterpret_cast<const bf16x8*>(&Wab[row * 128 + c8]);
  }
  __syncthreads();

  const int l = t & 63, q = l >> 4, r = l & 15;
  const int me = (t >> 6) * 16;

  f32x4 acc[8];

  // ---- A ----
#pragma unroll
  for (int nt = 0; nt < 8; ++nt) acc[nt] = (f32x4){0.f, 0.f, 0.f, 0.f};
  mm1(Xh, Wh, me, r, q, acc);
#pragma unroll
  for (int nt = 0; nt < 8; ++nt)
#pragma unroll
    for (int i = 0; i < 4; ++i) {
      int n = n0 + me + q * 4 + i;
      if (n < NN) Ab[(size_t)n * D + nt * 16 + r] = f2bf(acc[nt][i]);
    }
  __syncthreads();

  // ---- B ----
#pragma unroll
  for (int it = 0; it < 4; ++it) {
    int f = it * 512 + t, row = f >> 4, c8 = (f & 15) * 8;
    *reinterpret_cast<bf16x8*>(&Wh[row][c8]) =
        *reinterpret_cast<const bf16x8*>(&Wbb[row * 128 + c8]);
  }
  __syncthreads();
#pragma unroll
  for (int nt = 0; nt < 8; ++nt) acc[nt] = (f32x4){0.f, 0.f, 0.f, 0.f};
  mm1(Xh, Wh, me, r, q, acc);
#pragma unroll
  for (int nt = 0; nt < 8; ++nt)
#pragma unroll
    for (int i = 0; i < 4; ++i) {
      int n = n0 + me + q * 4 + i;
      if (n < NN) Bb[(size_t)n * D + nt * 16 + r] = f2bf(acc[nt][i]);
    }
  __syncthreads();

  // ---- M layer 1: h1 = relu(mw1.z + mb1), written back into Xh ----
#pragma unroll
  for (int it = 0; it < 4; ++it) {
    int f = it * 512 + t, row = f >> 4, c8 = (f & 15) * 8;
    *reinterpret_cast<bf16x8*>(&Wh[row][c8]) =
        *reinterpret_cast<const bf16x8*>(&m1b[row * 128 + c8]);
  }
  __syncthreads();
#pragma unroll
  for (int nt = 0; nt < 8; ++nt) acc[nt] = (f32x4){0.f, 0.f, 0.f, 0.f};
  mm1(Xh, Wh, me, r, q, acc);
  // each wave rewrites only its own 16-row stripe; other waves never read it
#pragma unroll
  for (int nt = 0; nt < 8; ++nt) {
    int col = nt * 16 + r;
    float b1 = mb1[col];
#pragma unroll
    for (int i = 0; i < 4; ++i)
      Xh[me + q * 4 + i][col] = f2bf(fmaxf(acc[nt][i] + b1, 0.0f));
  }
  __syncthreads();

  // ---- M layer 2: M = h1.mw2^T + mb2, stored bf16 ----
#pragma unroll
  for (int it = 0; it < 4; ++it) {
    int f = it * 512 + t, row = f >> 4, c8 = (f & 15) * 8;
    *reinterpret_cast<bf16x8*>(&Wh[row][c8]) =
        *reinterpret_cast<const bf16x8*>(&m2b[row * 128 + c8]);
  }
  __syncthreads();
#pragma unroll
  for (int nt = 0; nt < 8; ++nt) acc[nt] = (f32x4){0.f, 0.f, 0.f, 0.f};
  mm1(Xh, Wh, me, r, q, acc);
#pragma unroll
  for (int nt = 0; nt < 8; ++nt) {
    int col = nt * 16 + r;
    float b2 = mb2[col];
#pragma unroll
    for (int i = 0; i < 4; ++i) {
      int n = n0 + me + q * 4 + i;
      if (n < NN) Mb[(size_t)n * D + col] = f2bf(acc[nt][i] + b2);
    }
  }
}

// ---------------------------------------------------------------------------
// CSR build: two-level parallel scan (scan2 folded into scan3)
// ---------------------------------------------------------------------------
constexpr int SNB = 196;   // scan blocks: 196*256 = 50176 >= NN

__global__ __launch_bounds__(256) void k_scan1(const int* __restrict__ deg,
                                               int* __restrict__ pre,
                                               int* __restrict__ bsum)
{
  __shared__ int ps[256];
  const int t = threadIdx.x, b = blockIdx.x;
  const int i = b * 256 + t;
  int v = (i < NN) ? deg[i] : 0;
  ps[t] = v;
  __syncthreads();
  for (int off = 1; off < 256; off <<= 1) {
    int u = (t >= off) ? ps[t - off] : 0;
    __syncthreads();
    ps[t] += u;
    __syncthreads();
  }
  pre[i] = ps[t] - v;               // exclusive
  if (t == 255) bsum[b] = ps[255];  // block total
}

// scan2+scan3 fused: every block redundantly scans the 196 block sums in LDS,
// picks its own base, then writes rowptr/cursor for its 256 nodes.
__global__ __launch_bounds__(256) void k_scan23(const int* __restrict__ pre,
                                                const int* __restrict__ bsum,
                                                int* __restrict__ rowptr,
                                                int* __restrict__ cursor)
{
  __shared__ int ps[256];
  const int t = threadIdx.x, b = blockIdx.x;
  int v = (t < SNB) ? bsum[t] : 0;
  ps[t] = v;
  __syncthreads();
  for (int off = 1; off < 256; off <<= 1) {
    int u = (t >= off) ? ps[t - off] : 0;
    __syncthreads();
    ps[t] += u;
    __syncthreads();
  }
  const int base = (b == 0) ? 0 : ps[b - 1];  // exclusive prefix of block b
  const int i = b * 256 + t;
  if (i < NN) {
    int vv = pre[i] + base;
    rowptr[i] = vv;
    cursor[i] = vv;
  }
  if (i == 0) rowptr[NN] = NE;
}

// ---------------------------------------------------------------------------
// K2 v6: per-edge pass, bf16 MFMA. 128 edges/block, 8 waves, CSR order +
// XCD swizzle. W fragments read DIRECTLY from global: Wcb is 32KB bf16 ==
// exactly the 32KB L1, every wave re-reads it -> all-L1-hit after warmup.
// LDS = Xb only (~33.4KB) -> 4 blocks/CU (32 waves, occupancy cap).
// Epilogue unchanged from the proven round-14 form (no spills).
// ---------------------------------------------------------------------------
__global__ __launch_bounds__(512, 8) void k_edge_mfma(
    const unsigned short* __restrict__ zb, const int* __restrict__ ei,
    const int* __restrict__ etype,
    const unsigned short* __restrict__ Wcb, const float* __restrict__ tvg,
    const float* __restrict__ eb1, const float* __restrict__ ew2,
    const float* __restrict__ eb2,
    const unsigned short* __restrict__ Ab, const unsigned short* __restrict__ Bb,
    const int* __restrict__ eid, const int* __restrict__ de_perm,
    float* __restrict__ wexp_perm)
{
  __shared__ unsigned short Xb[128 * 128];   // 32KB, swizzled
  __shared__ unsigned short se[128], de[128];
  __shared__ unsigned char  tyg[128];

  const int t = threadIdx.x;
  // XCD swizzle (grid 4688 % 8 == 0 -> simple bijective form)
  const int nx = gridDim.x >> 3;
  const int sb = (blockIdx.x & 7) * nx + (blockIdx.x >> 3);
  const int e0 = sb * 128;

  if (t < 128) {
    int pos = e0 + t;
    if (pos < NE) {
      int e  = eid[pos];
      se[t]  = (unsigned short)ei[e];
      de[t]  = (unsigned short)de_perm[pos];
      tyg[t] = (unsigned char)etype[e];
    } else { se[t] = 0; de[t] = 0; tyg[t] = 0; }
  }
  __syncthreads();

  // stage X = |zb[src]-zb[dst]| (bf16 gathers, 256B/row)
#pragma unroll
  for (int it = 0; it < 8; ++it) {
    int f = it * 512 + t, r = f >> 5, c4 = f & 31;
    ushort4 a4 = *reinterpret_cast<const ushort4*>(&zb[(size_t)se[r] * D + c4 * 4]);
    ushort4 b4 = *reinterpret_cast<const ushort4*>(&zb[(size_t)de[r] * D + c4 * 4]);
    ushort4 v;
    v.x = f2bf(fabsf(bf2f(a4.x) - bf2f(b4.x)));
    v.y = f2bf(fabsf(bf2f(a4.y) - bf2f(b4.y)));
    v.z = f2bf(fabsf(bf2f(a4.z) - bf2f(b4.z)));
    v.w = f2bf(fabsf(bf2f(a4.w) - bf2f(b4.w)));
    int a = (r * 256 + c4 * 8) ^ ((r & 7) << 4);
    *reinterpret_cast<ushort4*>((char*)Xb + a) = v;
  }
  __syncthreads();

  const int l = t & 63, q = l >> 4, r = l & 15;
  const int me = (t >> 6) * 16;

  f32x4 acc[8];
#pragma unroll
  for (int nt = 0; nt < 8; ++nt) acc[nt] = (f32x4){0.f, 0.f, 0.f, 0.f};

  // MFMA: X from LDS, W straight from global (L1-resident 32KB)
#pragma unroll
  for (int ks = 0; ks < 4; ++ks) {
    int xa = ((me + r) * 256 + ks * 64 + q * 16) ^ ((r & 7) << 4);
    bf16x8 a = *reinterpret_cast<const bf16x8*>((const char*)Xb + xa);
#pragma unroll
    for (int nt = 0; nt < 8; ++nt) {
      bf16x8 b = *reinterpret_cast<const bf16x8*>(
          &Wcb[(nt * 16 + r) * 128 + ks * 32 + q * 8]);
      acc[nt] = __builtin_amdgcn_mfma_f32_16x16x32_bf16(a, b, acc[nt], 0, 0, 0);
    }
  }

  // epilogue: finish h, dot with ew2, reduce over 16 col-lanes
  int s[4], dd[4], ty[4];
#pragma unroll
  for (int i = 0; i < 4; ++i) {
    int el = me + q * 4 + i;
    s[i] = se[el]; dd[i] = de[el]; ty[i] = tyg[el];
  }
  float p[4] = {0.f, 0.f, 0.f, 0.f};
#pragma unroll
  for (int nt = 0; nt < 8; ++nt) {
    int col = nt * 16 + r;
    float e1  = eb1[col], w2 = ew2[col];
    float tva = tvg[col], tvb = tvg[128 + col];
#pragma unroll
    for (int i = 0; i < 4; ++i) {
      float h = acc[nt][i] + bf2f(Ab[(size_t)s[i] * D + col])
              + bf2f(Bb[(size_t)dd[i] * D + col]) + (ty[i] ? tvb : tva) + e1;
      p[i] += fmaxf(h, 0.f) * w2;
    }
  }
#pragma unroll
  for (int m = 1; m < 16; m <<= 1) {
#pragma unroll
    for (int i = 0; i < 4; ++i) p[i] += __shfl_xor(p[i], m);
  }
  if (r == 0) {
    float b2 = eb2[0];
#pragma unroll
    for (int i = 0; i < 4; ++i) {
      int pos = e0 + me + q * 4 + i;
      if (pos < NE) {
        float w = 1.0f / (1.0f + expf(-(p[i] + b2)));  // sigmoid
        wexp_perm[pos] = expf(w);                      // w in (0,1): stable
      }
    }
  }
}

// ---------------------------------------------------------------------------
// K3 v4: fused per-node aggregation + alpha + residual + LayerNorm.
// Mb gather loop unrolled x8; alpha written via scatter (measured ~free).
// ---------------------------------------------------------------------------
__global__ __launch_bounds__(256) void k_agg(
    const float* __restrict__ z, const float* __restrict__ wexp_perm,
    const unsigned short* __restrict__ Mb, const int* __restrict__ rowptr,
    const int* __restrict__ eid, const int* __restrict__ de_perm,
    const float* __restrict__ gamma, const float* __restrict__ beta,
    float* __restrict__ out, float* __restrict__ alpha_out)
{
  const int t = threadIdx.x;
  const int n = blockIdx.x * 4 + (t >> 6);
  const int l = t & 63;
  const int start = rowptr[n], end = rowptr[n + 1];

  float tot = 0.f;
  for (int base = start; base < end; base += 64) {
    if (base + l < end) tot += wexp_perm[base + l];
  }
#pragma unroll
  for (int off = 32; off; off >>= 1) tot += __shfl_xor(tot, off);
  const float inv = 1.0f / (tot + 1e-12f);

  float2 acc = make_float2(0.f, 0.f);
  for (int base = start; base < end; base += 64) {
    int cnt = min(64, end - base);
    int dd = 0;
    float al = 0.f;
    if (l < cnt) {
      int pos = base + l;
      al = wexp_perm[pos] * inv;
      dd = de_perm[pos];
      alpha_out[eid[pos]] = al;
    }
    int i = 0;
    for (; i + 8 <= cnt; i += 8) {
      float a[8]; int d[8]; ushort2 m[8];
#pragma unroll
      for (int j = 0; j < 8; ++j) {
        a[j] = __shfl(al, i + j);
        d[j] = __shfl(dd, i + j);
      }
#pragma unroll
      for (int j = 0; j < 8; ++j)
        m[j] = *reinterpret_cast<const ushort2*>(&Mb[(size_t)d[j] * D + l * 2]);
#pragma unroll
      for (int j = 0; j < 8; ++j) {
        acc.x = fmaf(a[j], bf2f(m[j].x), acc.x);
        acc.y = fmaf(a[j], bf2f(m[j].y), acc.y);
      }
    }
    for (; i < cnt; ++i) {
      float a = __shfl(al, i);
      int   d = __shfl(dd, i);
      ushort2 m = *reinterpret_cast<const ushort2*>(&Mb[(size_t)d * D + l * 2]);
      acc.x = fmaf(a, bf2f(m.x), acc.x);
      acc.y = fmaf(a, bf2f(m.y), acc.y);
    }
  }

  float2 xz = *reinterpret_cast<const float2*>(&z[(size_t)n * D + l * 2]);
  float x0 = xz.x + acc.x, x1 = xz.y + acc.y;
  float s = x0 + x1;
#pragma unroll
  for (int off = 32; off; off >>= 1) s += __shfl_xor(s, off);
  const float mu = s * (1.0f / 128.0f);
  float d0 = x0 - mu, d1 = x1 - mu;
  float q = d0 * d0 + d1 * d1;
#pragma unroll
  for (int off = 32; off; off >>= 1) q += __shfl_xor(q, off);
  const float rstd = rsqrtf(q * (1.0f / 128.0f) + 1e-5f);
  float2 g = *reinterpret_cast<const float2*>(&gamma[l * 2]);
  float2 b = *reinterpret_cast<const float2*>(&beta[l * 2]);
  float2 o = make_float2(d0 * rstd * g.x + b.x, d1 * rstd * g.y + b.y);
  *reinterpret_cast<float2*>(&out[(size_t)n * D + l * 2]) = o;
}

// ---------------------------------------------------------------------------
extern "C" void kernel_launch(void* const* d_in, const int* in_sizes, int n_in,
                              void* d_out, int out_size, void* d_ws, size_t ws_size,
                              hipStream_t stream)
{
  const float* z        = (const float*)d_in[0];
  const int*   ei       = (const int*)d_in[1];   // [2,E]: src row, then dst row
  const int*   etype    = (const int*)d_in[2];
  const float* type_emb = (const float*)d_in[3];
  const float* ew1      = (const float*)d_in[4];
  const float* eb1      = (const float*)d_in[5];
  const float* ew2      = (const float*)d_in[6];
  const float* eb2      = (const float*)d_in[7];
  const float* mw1      = (const float*)d_in[8];
  const float* mb1      = (const float*)d_in[9];
  const float* mw2      = (const float*)d_in[10];
  const float* mb2      = (const float*)d_in[11];
  const float* gamma    = (const float*)d_in[12];
  const float* beta     = (const float*)d_in[13];

  // workspace (float-unit offsets):
  // Ab|Bb|Mb|zb (bf16) | wexp_perm | ints | bf16 weights | tvg | scan
  float*          ws        = (float*)d_ws;
  unsigned short* Ab        = (unsigned short*)(ws);
  unsigned short* Bb        = (unsigned short*)(ws + 3200000);
  unsigned short* Mb        = (unsigned short*)(ws + 6400000);
  unsigned short* zb        = (unsigned short*)(ws + 9600000);
  float*          wexp_perm = ws + 12800000;
  int*            deg       = (int*)(ws + 13400000);
  int*            rowptr    = deg + 50000;
  int*            cursor    = rowptr + 50004;
  int*            eid       = cursor + 50000;
  int*            de_perm   = eid + 600000;
  unsigned short* Wcb       = (unsigned short*)(ws + 14800000);
  float*          tvg       = ws + 14810000;
  unsigned short* Wab       = (unsigned short*)(ws + 14820000);
  unsigned short* Wbb       = (unsigned short*)(ws + 14830000);
  unsigned short* m1b       = (unsigned short*)(ws + 14840000);
  unsigned short* m2b       = (unsigned short*)(ws + 14850000);
  int*            pre       = (int*)(ws + 14880000);   // 50176 ints
  int*            bsum      = (int*)(ws + 14940000);   // 256

  float* out       = (float*)d_out;
  float* alpha_out = out + (size_t)NN * D;

  hipMemsetAsync(deg, 0, 50000 * sizeof(int), stream);

  k_preph<<<64 + (NE + 255) / 256, 256, 0, stream>>>(
      ew1, type_emb, mw1, mw2, ei,
      Wab, Wbb, Wcb, m1b, m2b, tvg, deg);
  k_scan1<<<SNB, 256, 0, stream>>>(deg, pre, bsum);
  k_scan23<<<SNB, 256, 0, stream>>>(pre, bsum, rowptr, cursor);
  k_nodefill<<<NB_NODE + NB_FILL, 512, 0, stream>>>(
      z, Wab, Wbb, m1b, m2b, mb1, mb2, Ab, Bb, Mb, zb,
      ei, cursor, eid, de_perm);
  k_edge_mfma<<<(NE + 127) / 128, 512, 0, stream>>>(zb, ei, etype, Wcb, tvg,
                                                    eb1, ew2, eb2, Ab, Bb,
                                                    eid, de_perm, wexp_perm);
  k_agg<<<NN / 4, 256, 0, stream>>>(z, wexp_perm, Mb, rowptr, eid, de_perm,
                                    gamma, beta, out, alpha_out);
}

// Round 19
// 213.872 us; speedup vs baseline: 1.6695x; 1.6695x over previous
//
#include <hip/hip_runtime.h>
#include <math.h>

// Problem constants (fixed by the reference)
constexpr int NN  = 50000;   // nodes
constexpr int NE  = 600000;  // edges
constexpr int D   = 128;     // DIM == HID
constexpr int IND = 392;     // 3*DIM + TEMB

constexpr int NB_NODE = (NN + 127) / 128;          // 391 node blocks
constexpr int NB_FILL = (NE + 511) / 512;          // 1172 fill blocks

typedef __attribute__((ext_vector_type(8))) short bf16x8;   // 8 bf16 = 4 VGPR
typedef __attribute__((ext_vector_type(4))) float f32x4;    // MFMA accumulator

__device__ __forceinline__ float4 ld4(const float* p) { return *reinterpret_cast<const float4*>(p); }

// float -> bf16 (RNE) and back
__device__ __forceinline__ unsigned short f2bf(float f) {
  unsigned int u = __float_as_uint(f);
  u += 0x7fffu + ((u >> 16) & 1u);
  return (unsigned short)(u >> 16);
}
__device__ __forceinline__ float bf2f(unsigned short s) {
  return __uint_as_float(((unsigned int)s) << 16);
}

// ---------------------------------------------------------------------------
// K0: merged pre-pass + histogram. Blocks 0..63: weight conversion.
// Blocks 64..: degree histogram.
// ---------------------------------------------------------------------------
__global__ __launch_bounds__(256) void k_preph(
    const float* __restrict__ ew1, const float* __restrict__ type_emb,
    const float* __restrict__ mw1, const float* __restrict__ mw2,
    const int* __restrict__ ei,
    unsigned short* __restrict__ Wab, unsigned short* __restrict__ Wbb,
    unsigned short* __restrict__ Wcb,
    unsigned short* __restrict__ m1b, unsigned short* __restrict__ m2b,
    float* __restrict__ tvg, int* __restrict__ deg)
{
  const int b = blockIdx.x, t = threadIdx.x;
  if (b < 64) {
    int g = b * 256 + t;   // 0..16383
    int o = g >> 7, k = g & 127;
    Wab[g] = f2bf(ew1[o * IND + k]);
    Wbb[g] = f2bf(ew1[o * IND + 128 + k]);
    Wcb[g] = f2bf(ew1[o * IND + 256 + k]);
    m1b[g] = f2bf(mw1[g]);
    m2b[g] = f2bf(mw2[g]);
    if (b == 0) {
      int oo = t & 127, ty = t >> 7;
      float s = 0.f;
#pragma unroll
      for (int j = 0; j < 8; ++j) s += ew1[oo * IND + 384 + j] * type_emb[ty * 8 + j];
      tvg[ty * 128 + oo] = s;
    }
  } else {
    int e = (b - 64) * 256 + t;
    if (e < NE) atomicAdd(&deg[ei[e]], 1);
  }
}

// ---------------------------------------------------------------------------
// 1-term MFMA micro-GEMM: acc[nt] += X-tile(rows me..me+15) . W^T  (K=128)
// ---------------------------------------------------------------------------
__device__ __forceinline__ void mm1(
    const unsigned short (*X)[136], const unsigned short (*W)[136],
    int me, int r, int q, f32x4 acc[8])
{
#pragma unroll
  for (int ks = 0; ks < 4; ++ks) {
    bf16x8 a = *reinterpret_cast<const bf16x8*>(&X[me + r][ks * 32 + q * 8]);
#pragma unroll
    for (int nt = 0; nt < 8; ++nt) {
      bf16x8 b = *reinterpret_cast<const bf16x8*>(&W[nt * 16 + r][ks * 32 + q * 8]);
      acc[nt] = __builtin_amdgcn_mfma_f32_16x16x32_bf16(a, b, acc[nt], 0, 0, 0);
    }
  }
}

// ---------------------------------------------------------------------------
// K1: MERGED node-precompute + CSR fill.
// Blocks 0..NB_NODE-1: per-node MFMA precompute (512 thr, 8 waves, 69.6KB LDS).
// Blocks NB_NODE..  : CSR fill (atomic cursor scatter; LDS unused).
// ---------------------------------------------------------------------------
__global__ __launch_bounds__(512, 2) void k_nodefill(
    const float* __restrict__ z,
    const unsigned short* __restrict__ Wab, const unsigned short* __restrict__ Wbb,
    const unsigned short* __restrict__ m1b, const unsigned short* __restrict__ m2b,
    const float* __restrict__ mb1, const float* __restrict__ mb2,
    unsigned short* __restrict__ Ab, unsigned short* __restrict__ Bb,
    unsigned short* __restrict__ Mb, unsigned short* __restrict__ zb,
    const int* __restrict__ ei, int* __restrict__ cursor,
    int* __restrict__ eid, int* __restrict__ de_perm)
{
  __shared__ unsigned short Xh[128][136];
  __shared__ unsigned short Wh[128][136];
  const int t = threadIdx.x;

  if (blockIdx.x >= NB_NODE) {
    // ---------------- CSR fill part ----------------
    int e = (blockIdx.x - NB_NODE) * 512 + t;
    if (e < NE) {
      int pos = atomicAdd(&cursor[ei[e]], 1);
      eid[pos] = e;
      de_perm[pos] = ei[NE + e];
    }
    return;
  }

  // ---------------- node precompute part ----------------
  const int n0 = blockIdx.x * 128;

  // stage z (bf16) into Xh; also write zb
#pragma unroll
  for (int it = 0; it < 8; ++it) {
    int f = it * 512 + t, rr = f >> 5, c4 = (f & 31) * 4;
    int n = n0 + rr; if (n >= NN) n = NN - 1;
    float4 v = ld4(&z[(size_t)n * D + c4]);
    ushort4 hi;
    hi.x = f2bf(v.x); hi.y = f2bf(v.y); hi.z = f2bf(v.z); hi.w = f2bf(v.w);
    *reinterpret_cast<ushort4*>(&Xh[rr][c4]) = hi;
    if (n0 + rr < NN)
      *reinterpret_cast<ushort4*>(&zb[(size_t)(n0 + rr) * D + c4]) = hi;
  }
  // stage Wa
#pragma unroll
  for (int it = 0; it < 4; ++it) {
    int f = it * 512 + t, row = f >> 4, c8 = (f & 15) * 8;
    *reinterpret_cast<bf16x8*>(&Wh[row][c8]) =
        *reinterpret_cast<const bf16x8*>(&Wab[row * 128 + c8]);
  }
  __syncthreads();

  const int l = t & 63, q = l >> 4, r = l & 15;
  const int me = (t >> 6) * 16;

  f32x4 acc[8];

  // ---- A ----
#pragma unroll
  for (int nt = 0; nt < 8; ++nt) acc[nt] = (f32x4){0.f, 0.f, 0.f, 0.f};
  mm1(Xh, Wh, me, r, q, acc);
#pragma unroll
  for (int nt = 0; nt < 8; ++nt)
#pragma unroll
    for (int i = 0; i < 4; ++i) {
      int n = n0 + me + q * 4 + i;
      if (n < NN) Ab[(size_t)n * D + nt * 16 + r] = f2bf(acc[nt][i]);
    }
  __syncthreads();

  // ---- B ----
#pragma unroll
  for (int it = 0; it < 4; ++it) {
    int f = it * 512 + t, row = f >> 4, c8 = (f & 15) * 8;
    *reinterpret_cast<bf16x8*>(&Wh[row][c8]) =
        *reinterpret_cast<const bf16x8*>(&Wbb[row * 128 + c8]);
  }
  __syncthreads();
#pragma unroll
  for (int nt = 0; nt < 8; ++nt) acc[nt] = (f32x4){0.f, 0.f, 0.f, 0.f};
  mm1(Xh, Wh, me, r, q, acc);
#pragma unroll
  for (int nt = 0; nt < 8; ++nt)
#pragma unroll
    for (int i = 0; i < 4; ++i) {
      int n = n0 + me + q * 4 + i;
      if (n < NN) Bb[(size_t)n * D + nt * 16 + r] = f2bf(acc[nt][i]);
    }
  __syncthreads();

  // ---- M layer 1: h1 = relu(mw1.z + mb1), written back into Xh ----
#pragma unroll
  for (int it = 0; it < 4; ++it) {
    int f = it * 512 + t, row = f >> 4, c8 = (f & 15) * 8;
    *reinterpret_cast<bf16x8*>(&Wh[row][c8]) =
        *reinterpret_cast<const bf16x8*>(&m1b[row * 128 + c8]);
  }
  __syncthreads();
#pragma unroll
  for (int nt = 0; nt < 8; ++nt) acc[nt] = (f32x4){0.f, 0.f, 0.f, 0.f};
  mm1(Xh, Wh, me, r, q, acc);
  // each wave rewrites only its own 16-row stripe; other waves never read it
#pragma unroll
  for (int nt = 0; nt < 8; ++nt) {
    int col = nt * 16 + r;
    float b1 = mb1[col];
#pragma unroll
    for (int i = 0; i < 4; ++i)
      Xh[me + q * 4 + i][col] = f2bf(fmaxf(acc[nt][i] + b1, 0.0f));
  }
  __syncthreads();

  // ---- M layer 2: M = h1.mw2^T + mb2, stored bf16 ----
#pragma unroll
  for (int it = 0; it < 4; ++it) {
    int f = it * 512 + t, row = f >> 4, c8 = (f & 15) * 8;
    *reinterpret_cast<bf16x8*>(&Wh[row][c8]) =
        *reinterpret_cast<const bf16x8*>(&m2b[row * 128 + c8]);
  }
  __syncthreads();
#pragma unroll
  for (int nt = 0; nt < 8; ++nt) acc[nt] = (f32x4){0.f, 0.f, 0.f, 0.f};
  mm1(Xh, Wh, me, r, q, acc);
#pragma unroll
  for (int nt = 0; nt < 8; ++nt) {
    int col = nt * 16 + r;
    float b2 = mb2[col];
#pragma unroll
    for (int i = 0; i < 4; ++i) {
      int n = n0 + me + q * 4 + i;
      if (n < NN) Mb[(size_t)n * D + col] = f2bf(acc[nt][i] + b2);
    }
  }
}

// ---------------------------------------------------------------------------
// CSR build: two-level parallel scan (scan2 folded into scan3)
// ---------------------------------------------------------------------------
constexpr int SNB = 196;   // scan blocks: 196*256 = 50176 >= NN

__global__ __launch_bounds__(256) void k_scan1(const int* __restrict__ deg,
                                               int* __restrict__ pre,
                                               int* __restrict__ bsum)
{
  __shared__ int ps[256];
  const int t = threadIdx.x, b = blockIdx.x;
  const int i = b * 256 + t;
  int v = (i < NN) ? deg[i] : 0;
  ps[t] = v;
  __syncthreads();
  for (int off = 1; off < 256; off <<= 1) {
    int u = (t >= off) ? ps[t - off] : 0;
    __syncthreads();
    ps[t] += u;
    __syncthreads();
  }
  pre[i] = ps[t] - v;               // exclusive
  if (t == 255) bsum[b] = ps[255];  // block total
}

// scan2+scan3 fused: every block redundantly scans the 196 block sums in LDS,
// picks its own base, then writes rowptr/cursor for its 256 nodes.
__global__ __launch_bounds__(256) void k_scan23(const int* __restrict__ pre,
                                                const int* __restrict__ bsum,
                                                int* __restrict__ rowptr,
                                                int* __restrict__ cursor)
{
  __shared__ int ps[256];
  const int t = threadIdx.x, b = blockIdx.x;
  int v = (t < SNB) ? bsum[t] : 0;
  ps[t] = v;
  __syncthreads();
  for (int off = 1; off < 256; off <<= 1) {
    int u = (t >= off) ? ps[t - off] : 0;
    __syncthreads();
    ps[t] += u;
    __syncthreads();
  }
  const int base = (b == 0) ? 0 : ps[b - 1];  // exclusive prefix of block b
  const int i = b * 256 + t;
  if (i < NN) {
    int vv = pre[i] + base;
    rowptr[i] = vv;
    cursor[i] = vv;
  }
  if (i == 0) rowptr[NN] = NE;
}

// ---------------------------------------------------------------------------
// K2 (round-14/17 PROVEN form, frozen): per-edge pass, bf16 MFMA.
// 128 edges/block, 8 waves, CSR order + XCD swizzle. LDS ~49KB -> 3 blk/CU.
// XOR swizzle; W staged in two 64-row halves in one 16KB buffer.
// ---------------------------------------------------------------------------
__global__ __launch_bounds__(512, 6) void k_edge_mfma(
    const unsigned short* __restrict__ zb, const int* __restrict__ ei,
    const int* __restrict__ etype,
    const unsigned short* __restrict__ Wcb, const float* __restrict__ tvg,
    const float* __restrict__ eb1, const float* __restrict__ ew2,
    const float* __restrict__ eb2,
    const unsigned short* __restrict__ Ab, const unsigned short* __restrict__ Bb,
    const int* __restrict__ eid, const int* __restrict__ de_perm,
    float* __restrict__ wexp_perm)
{
  __shared__ unsigned short Xb[128 * 128];   // 32KB, swizzled
  __shared__ unsigned short Wb[64 * 128];    // 16KB, swizzled, 2-phase
  __shared__ unsigned short se[128], de[128];
  __shared__ unsigned char  tyg[128];

  const int t = threadIdx.x;
  // XCD swizzle (grid 4688 % 8 == 0 -> simple bijective form)
  const int nx = gridDim.x >> 3;
  const int sb = (blockIdx.x & 7) * nx + (blockIdx.x >> 3);
  const int e0 = sb * 128;

  if (t < 128) {
    int pos = e0 + t;
    if (pos < NE) {
      int e  = eid[pos];
      se[t]  = (unsigned short)ei[e];
      de[t]  = (unsigned short)de_perm[pos];
      tyg[t] = (unsigned char)etype[e];
    } else { se[t] = 0; de[t] = 0; tyg[t] = 0; }
  }
  // stage W half 0 (global rows 0..63)
#pragma unroll
  for (int it = 0; it < 2; ++it) {
    int f = it * 512 + t, row = f >> 4, c = f & 15;
    int a = (row * 256 + c * 16) ^ ((row & 7) << 4);
    *reinterpret_cast<bf16x8*>((char*)Wb + a) =
        *reinterpret_cast<const bf16x8*>(&Wcb[row * 128 + c * 8]);
  }
  __syncthreads();

  // stage X = |zb[src]-zb[dst]| (bf16 gathers, 256B/row)
#pragma unroll
  for (int it = 0; it < 8; ++it) {
    int f = it * 512 + t, r = f >> 5, c4 = f & 31;
    ushort4 a4 = *reinterpret_cast<const ushort4*>(&zb[(size_t)se[r] * D + c4 * 4]);
    ushort4 b4 = *reinterpret_cast<const ushort4*>(&zb[(size_t)de[r] * D + c4 * 4]);
    ushort4 v;
    v.x = f2bf(fabsf(bf2f(a4.x) - bf2f(b4.x)));
    v.y = f2bf(fabsf(bf2f(a4.y) - bf2f(b4.y)));
    v.z = f2bf(fabsf(bf2f(a4.z) - bf2f(b4.z)));
    v.w = f2bf(fabsf(bf2f(a4.w) - bf2f(b4.w)));
    int a = (r * 256 + c4 * 8) ^ ((r & 7) << 4);
    *reinterpret_cast<ushort4*>((char*)Xb + a) = v;
  }
  __syncthreads();

  const int l = t & 63, q = l >> 4, r = l & 15;
  const int me = (t >> 6) * 16;

  f32x4 acc[8];
#pragma unroll
  for (int nt = 0; nt < 8; ++nt) acc[nt] = (f32x4){0.f, 0.f, 0.f, 0.f};

  // phase 0: nt 0..3
#pragma unroll
  for (int ks = 0; ks < 4; ++ks) {
    int xa = ((me + r) * 256 + ks * 64 + q * 16) ^ ((r & 7) << 4);
    bf16x8 a = *reinterpret_cast<const bf16x8*>((const char*)Xb + xa);
#pragma unroll
    for (int ntl = 0; ntl < 4; ++ntl) {
      int wrow = ntl * 16 + r;
      int wa = (wrow * 256 + ks * 64 + q * 16) ^ ((wrow & 7) << 4);
      bf16x8 b = *reinterpret_cast<const bf16x8*>((const char*)Wb + wa);
      acc[ntl] = __builtin_amdgcn_mfma_f32_16x16x32_bf16(a, b, acc[ntl], 0, 0, 0);
    }
  }
  __syncthreads();   // all waves done reading W half 0

  // stage W half 1 (global rows 64..127)
#pragma unroll
  for (int it = 0; it < 2; ++it) {
    int f = it * 512 + t, row = f >> 4, c = f & 15;
    int a = (row * 256 + c * 16) ^ ((row & 7) << 4);
    *reinterpret_cast<bf16x8*>((char*)Wb + a) =
        *reinterpret_cast<const bf16x8*>(&Wcb[(64 + row) * 128 + c * 8]);
  }
  __syncthreads();

  // phase 1: nt 4..7
#pragma unroll
  for (int ks = 0; ks < 4; ++ks) {
    int xa = ((me + r) * 256 + ks * 64 + q * 16) ^ ((r & 7) << 4);
    bf16x8 a = *reinterpret_cast<const bf16x8*>((const char*)Xb + xa);
#pragma unroll
    for (int ntl = 0; ntl < 4; ++ntl) {
      int wrow = ntl * 16 + r;
      int wa = (wrow * 256 + ks * 64 + q * 16) ^ ((wrow & 7) << 4);
      bf16x8 b = *reinterpret_cast<const bf16x8*>((const char*)Wb + wa);
      acc[4 + ntl] = __builtin_amdgcn_mfma_f32_16x16x32_bf16(a, b, acc[4 + ntl], 0, 0, 0);
    }
  }

  // epilogue: finish h, dot with ew2, reduce over 16 col-lanes
  int s[4], dd[4], ty[4];
#pragma unroll
  for (int i = 0; i < 4; ++i) {
    int el = me + q * 4 + i;
    s[i] = se[el]; dd[i] = de[el]; ty[i] = tyg[el];
  }
  float p[4] = {0.f, 0.f, 0.f, 0.f};
#pragma unroll
  for (int nt = 0; nt < 8; ++nt) {
    int col = nt * 16 + r;
    float e1  = eb1[col], w2 = ew2[col];
    float tva = tvg[col], tvb = tvg[128 + col];
#pragma unroll
    for (int i = 0; i < 4; ++i) {
      float h = acc[nt][i] + bf2f(Ab[(size_t)s[i] * D + col])
              + bf2f(Bb[(size_t)dd[i] * D + col]) + (ty[i] ? tvb : tva) + e1;
      p[i] += fmaxf(h, 0.f) * w2;
    }
  }
#pragma unroll
  for (int m = 1; m < 16; m <<= 1) {
#pragma unroll
    for (int i = 0; i < 4; ++i) p[i] += __shfl_xor(p[i], m);
  }
  if (r == 0) {
    float b2 = eb2[0];
#pragma unroll
    for (int i = 0; i < 4; ++i) {
      int pos = e0 + me + q * 4 + i;
      if (pos < NE) {
        float w = 1.0f / (1.0f + expf(-(p[i] + b2)));  // sigmoid
        wexp_perm[pos] = expf(w);                      // w in (0,1): stable
      }
    }
  }
}

// ---------------------------------------------------------------------------
// K3: fused per-node aggregation + alpha + residual + LayerNorm.
// Mb gather loop unrolled x8; alpha scatter measured ~neutral (r13).
// ---------------------------------------------------------------------------
__global__ __launch_bounds__(256) void k_agg(
    const float* __restrict__ z, const float* __restrict__ wexp_perm,
    const unsigned short* __restrict__ Mb, const int* __restrict__ rowptr,
    const int* __restrict__ eid, const int* __restrict__ de_perm,
    const float* __restrict__ gamma, const float* __restrict__ beta,
    float* __restrict__ out, float* __restrict__ alpha_out)
{
  const int t = threadIdx.x;
  const int n = blockIdx.x * 4 + (t >> 6);
  const int l = t & 63;
  const int start = rowptr[n], end = rowptr[n + 1];

  float tot = 0.f;
  for (int base = start; base < end; base += 64) {
    if (base + l < end) tot += wexp_perm[base + l];
  }
#pragma unroll
  for (int off = 32; off; off >>= 1) tot += __shfl_xor(tot, off);
  const float inv = 1.0f / (tot + 1e-12f);

  float2 acc = make_float2(0.f, 0.f);
  for (int base = start; base < end; base += 64) {
    int cnt = min(64, end - base);
    int dd = 0;
    float al = 0.f;
    if (l < cnt) {
      int pos = base + l;
      al = wexp_perm[pos] * inv;
      dd = de_perm[pos];
      alpha_out[eid[pos]] = al;
    }
    int i = 0;
    for (; i + 8 <= cnt; i += 8) {
      float a[8]; int d[8]; ushort2 m[8];
#pragma unroll
      for (int j = 0; j < 8; ++j) {
        a[j] = __shfl(al, i + j);
        d[j] = __shfl(dd, i + j);
      }
#pragma unroll
      for (int j = 0; j < 8; ++j)
        m[j] = *reinterpret_cast<const ushort2*>(&Mb[(size_t)d[j] * D + l * 2]);
#pragma unroll
      for (int j = 0; j < 8; ++j) {
        acc.x = fmaf(a[j], bf2f(m[j].x), acc.x);
        acc.y = fmaf(a[j], bf2f(m[j].y), acc.y);
      }
    }
    for (; i < cnt; ++i) {
      float a = __shfl(al, i);
      int   d = __shfl(dd, i);
      ushort2 m = *reinterpret_cast<const ushort2*>(&Mb[(size_t)d * D + l * 2]);
      acc.x = fmaf(a, bf2f(m.x), acc.x);
      acc.y = fmaf(a, bf2f(m.y), acc.y);
    }
  }

  float2 xz = *reinterpret_cast<const float2*>(&z[(size_t)n * D + l * 2]);
  float x0 = xz.x + acc.x, x1 = xz.y + acc.y;
  float s = x0 + x1;
#pragma unroll
  for (int off = 32; off; off >>= 1) s += __shfl_xor(s, off);
  const float mu = s * (1.0f / 128.0f);
  float d0 = x0 - mu, d1 = x1 - mu;
  float q = d0 * d0 + d1 * d1;
#pragma unroll
  for (int off = 32; off; off >>= 1) q += __shfl_xor(q, off);
  const float rstd = rsqrtf(q * (1.0f / 128.0f) + 1e-5f);
  float2 g = *reinterpret_cast<const float2*>(&gamma[l * 2]);
  float2 b = *reinterpret_cast<const float2*>(&beta[l * 2]);
  float2 o = make_float2(d0 * rstd * g.x + b.x, d1 * rstd * g.y + b.y);
  *reinterpret_cast<float2*>(&out[(size_t)n * D + l * 2]) = o;
}

// ---------------------------------------------------------------------------
extern "C" void kernel_launch(void* const* d_in, const int* in_sizes, int n_in,
                              void* d_out, int out_size, void* d_ws, size_t ws_size,
                              hipStream_t stream)
{
  const float* z        = (const float*)d_in[0];
  const int*   ei       = (const int*)d_in[1];   // [2,E]: src row, then dst row
  const int*   etype    = (const int*)d_in[2];
  const float* type_emb = (const float*)d_in[3];
  const float* ew1      = (const float*)d_in[4];
  const float* eb1      = (const float*)d_in[5];
  const float* ew2      = (const float*)d_in[6];
  const float* eb2      = (const float*)d_in[7];
  const float* mw1      = (const float*)d_in[8];
  const float* mb1      = (const float*)d_in[9];
  const float* mw2      = (const float*)d_in[10];
  const float* mb2      = (const float*)d_in[11];
  const float* gamma    = (const float*)d_in[12];
  const float* beta     = (const float*)d_in[13];

  // workspace (float-unit offsets):
  // Ab|Bb|Mb|zb (bf16) | wexp_perm | ints | bf16 weights | tvg | scan
  float*          ws        = (float*)d_ws;
  unsigned short* Ab        = (unsigned short*)(ws);
  unsigned short* Bb        = (unsigned short*)(ws + 3200000);
  unsigned short* Mb        = (unsigned short*)(ws + 6400000);
  unsigned short* zb        = (unsigned short*)(ws + 9600000);
  float*          wexp_perm = ws + 12800000;
  int*            deg       = (int*)(ws + 13400000);
  int*            rowptr    = deg + 50000;
  int*            cursor    = rowptr + 50004;
  int*            eid       = cursor + 50000;
  int*            de_perm   = eid + 600000;
  unsigned short* Wcb       = (unsigned short*)(ws + 14800000);
  float*          tvg       = ws + 14810000;
  unsigned short* Wab       = (unsigned short*)(ws + 14820000);
  unsigned short* Wbb       = (unsigned short*)(ws + 14830000);
  unsigned short* m1b       = (unsigned short*)(ws + 14840000);
  unsigned short* m2b       = (unsigned short*)(ws + 14850000);
  int*            pre       = (int*)(ws + 14880000);   // 50176 ints
  int*            bsum      = (int*)(ws + 14940000);   // 256

  float* out       = (float*)d_out;
  float* alpha_out = out + (size_t)NN * D;

  hipMemsetAsync(deg, 0, 50000 * sizeof(int), stream);

  k_preph<<<64 + (NE + 255) / 256, 256, 0, stream>>>(
      ew1, type_emb, mw1, mw2, ei,
      Wab, Wbb, Wcb, m1b, m2b, tvg, deg);
  k_scan1<<<SNB, 256, 0, stream>>>(deg, pre, bsum);
  k_scan23<<<SNB, 256, 0, stream>>>(pre, bsum, rowptr, cursor);
  k_nodefill<<<NB_NODE + NB_FILL, 512, 0, stream>>>(
      z, Wab, Wbb, m1b, m2b, mb1, mb2, Ab, Bb, Mb, zb,
      ei, cursor, eid, de_perm);
  k_edge_mfma<<<(NE + 127) / 128, 512, 0, stream>>>(zb, ei, etype, Wcb, tvg,
                                                    eb1, ew2, eb2, Ab, Bb,
                                                    eid, de_perm, wexp_perm);
  k_agg<<<NN / 4, 256, 0, stream>>>(z, wexp_perm, Mb, rowptr, eid, de_perm,
                                    gamma, beta, out, alpha_out);
}

// Round 20
// 211.320 us; speedup vs baseline: 1.6897x; 1.0121x over previous
//
#include <hip/hip_runtime.h>
#include <math.h>

// Problem constants (fixed by the reference)
constexpr int NN  = 50000;   // nodes
constexpr int NE  = 600000;  // edges
constexpr int D   = 128;     // DIM == HID
constexpr int IND = 392;     // 3*DIM + TEMB

constexpr int NB_NODE = (NN + 127) / 128;          // 391 node blocks
constexpr int NB_FILL = (NE + 511) / 512;          // 1172 fill blocks

typedef __attribute__((ext_vector_type(8))) short bf16x8;   // 8 bf16 = 4 VGPR
typedef __attribute__((ext_vector_type(4))) float f32x4;    // MFMA accumulator

__device__ __forceinline__ float4 ld4(const float* p) { return *reinterpret_cast<const float4*>(p); }

// float -> bf16 (RNE) and back
__device__ __forceinline__ unsigned short f2bf(float f) {
  unsigned int u = __float_as_uint(f);
  u += 0x7fffu + ((u >> 16) & 1u);
  return (unsigned short)(u >> 16);
}
__device__ __forceinline__ float bf2f(unsigned short s) {
  return __uint_as_float(((unsigned int)s) << 16);
}

// ---------------------------------------------------------------------------
// K0: merged pre-pass + histogram. Blocks 0..63: weight conversion.
// Blocks 64..: degree histogram.
// ---------------------------------------------------------------------------
__global__ __launch_bounds__(256) void k_preph(
    const float* __restrict__ ew1, const float* __restrict__ type_emb,
    const float* __restrict__ mw1, const float* __restrict__ mw2,
    const int* __restrict__ ei,
    unsigned short* __restrict__ Wab, unsigned short* __restrict__ Wbb,
    unsigned short* __restrict__ Wcb,
    unsigned short* __restrict__ m1b, unsigned short* __restrict__ m2b,
    float* __restrict__ tvg, int* __restrict__ deg)
{
  const int b = blockIdx.x, t = threadIdx.x;
  if (b < 64) {
    int g = b * 256 + t;   // 0..16383
    int o = g >> 7, k = g & 127;
    Wab[g] = f2bf(ew1[o * IND + k]);
    Wbb[g] = f2bf(ew1[o * IND + 128 + k]);
    Wcb[g] = f2bf(ew1[o * IND + 256 + k]);
    m1b[g] = f2bf(mw1[g]);
    m2b[g] = f2bf(mw2[g]);
    if (b == 0) {
      int oo = t & 127, ty = t >> 7;
      float s = 0.f;
#pragma unroll
      for (int j = 0; j < 8; ++j) s += ew1[oo * IND + 384 + j] * type_emb[ty * 8 + j];
      tvg[ty * 128 + oo] = s;
    }
  } else {
    int e = (b - 64) * 256 + t;
    if (e < NE) atomicAdd(&deg[ei[e]], 1);
  }
}

// ---------------------------------------------------------------------------
// 1-term MFMA micro-GEMM: acc[nt] += X-tile(rows me..me+15) . W^T  (K=128)
// ---------------------------------------------------------------------------
__device__ __forceinline__ void mm1(
    const unsigned short (*X)[136], const unsigned short (*W)[136],
    int me, int r, int q, f32x4 acc[8])
{
#pragma unroll
  for (int ks = 0; ks < 4; ++ks) {
    bf16x8 a = *reinterpret_cast<const bf16x8*>(&X[me + r][ks * 32 + q * 8]);
#pragma unroll
    for (int nt = 0; nt < 8; ++nt) {
      bf16x8 b = *reinterpret_cast<const bf16x8*>(&W[nt * 16 + r][ks * 32 + q * 8]);
      acc[nt] = __builtin_amdgcn_mfma_f32_16x16x32_bf16(a, b, acc[nt], 0, 0, 0);
    }
  }
}

// ---------------------------------------------------------------------------
// K1: MERGED node-precompute + CSR fill.
// Blocks 0..NB_NODE-1: per-node MFMA precompute (512 thr, 8 waves, 69.6KB LDS).
// Blocks NB_NODE..  : CSR fill (atomic cursor scatter; LDS unused).
// ---------------------------------------------------------------------------
__global__ __launch_bounds__(512, 2) void k_nodefill(
    const float* __restrict__ z,
    const unsigned short* __restrict__ Wab, const unsigned short* __restrict__ Wbb,
    const unsigned short* __restrict__ m1b, const unsigned short* __restrict__ m2b,
    const float* __restrict__ mb1, const float* __restrict__ mb2,
    unsigned short* __restrict__ Ab, unsigned short* __restrict__ Bb,
    unsigned short* __restrict__ Mb, unsigned short* __restrict__ zb,
    const int* __restrict__ ei, int* __restrict__ cursor,
    int* __restrict__ eid, int* __restrict__ de_perm)
{
  __shared__ unsigned short Xh[128][136];
  __shared__ unsigned short Wh[128][136];
  const int t = threadIdx.x;

  if (blockIdx.x >= NB_NODE) {
    // ---------------- CSR fill part ----------------
    int e = (blockIdx.x - NB_NODE) * 512 + t;
    if (e < NE) {
      int pos = atomicAdd(&cursor[ei[e]], 1);
      eid[pos] = e;
      de_perm[pos] = ei[NE + e];
    }
    return;
  }

  // ---------------- node precompute part ----------------
  const int n0 = blockIdx.x * 128;

  // stage z (bf16) into Xh; also write zb
#pragma unroll
  for (int it = 0; it < 8; ++it) {
    int f = it * 512 + t, rr = f >> 5, c4 = (f & 31) * 4;
    int n = n0 + rr; if (n >= NN) n = NN - 1;
    float4 v = ld4(&z[(size_t)n * D + c4]);
    ushort4 hi;
    hi.x = f2bf(v.x); hi.y = f2bf(v.y); hi.z = f2bf(v.z); hi.w = f2bf(v.w);
    *reinterpret_cast<ushort4*>(&Xh[rr][c4]) = hi;
    if (n0 + rr < NN)
      *reinterpret_cast<ushort4*>(&zb[(size_t)(n0 + rr) * D + c4]) = hi;
  }
  // stage Wa
#pragma unroll
  for (int it = 0; it < 4; ++it) {
    int f = it * 512 + t, row = f >> 4, c8 = (f & 15) * 8;
    *reinterpret_cast<bf16x8*>(&Wh[row][c8]) =
        *reinterpret_cast<const bf16x8*>(&Wab[row * 128 + c8]);
  }
  __syncthreads();

  const int l = t & 63, q = l >> 4, r = l & 15;
  const int me = (t >> 6) * 16;

  f32x4 acc[8];

  // ---- A ----
#pragma unroll
  for (int nt = 0; nt < 8; ++nt) acc[nt] = (f32x4){0.f, 0.f, 0.f, 0.f};
  mm1(Xh, Wh, me, r, q, acc);
#pragma unroll
  for (int nt = 0; nt < 8; ++nt)
#pragma unroll
    for (int i = 0; i < 4; ++i) {
      int n = n0 + me + q * 4 + i;
      if (n < NN) Ab[(size_t)n * D + nt * 16 + r] = f2bf(acc[nt][i]);
    }
  __syncthreads();

  // ---- B ----
#pragma unroll
  for (int it = 0; it < 4; ++it) {
    int f = it * 512 + t, row = f >> 4, c8 = (f & 15) * 8;
    *reinterpret_cast<bf16x8*>(&Wh[row][c8]) =
        *reinterpret_cast<const bf16x8*>(&Wbb[row * 128 + c8]);
  }
  __syncthreads();
#pragma unroll
  for (int nt = 0; nt < 8; ++nt) acc[nt] = (f32x4){0.f, 0.f, 0.f, 0.f};
  mm1(Xh, Wh, me, r, q, acc);
#pragma unroll
  for (int nt = 0; nt < 8; ++nt)
#pragma unroll
    for (int i = 0; i < 4; ++i) {
      int n = n0 + me + q * 4 + i;
      if (n < NN) Bb[(size_t)n * D + nt * 16 + r] = f2bf(acc[nt][i]);
    }
  __syncthreads();

  // ---- M layer 1: h1 = relu(mw1.z + mb1), written back into Xh ----
#pragma unroll
  for (int it = 0; it < 4; ++it) {
    int f = it * 512 + t, row = f >> 4, c8 = (f & 15) * 8;
    *reinterpret_cast<bf16x8*>(&Wh[row][c8]) =
        *reinterpret_cast<const bf16x8*>(&m1b[row * 128 + c8]);
  }
  __syncthreads();
#pragma unroll
  for (int nt = 0; nt < 8; ++nt) acc[nt] = (f32x4){0.f, 0.f, 0.f, 0.f};
  mm1(Xh, Wh, me, r, q, acc);
  // each wave rewrites only its own 16-row stripe; other waves never read it
#pragma unroll
  for (int nt = 0; nt < 8; ++nt) {
    int col = nt * 16 + r;
    float b1 = mb1[col];
#pragma unroll
    for (int i = 0; i < 4; ++i)
      Xh[me + q * 4 + i][col] = f2bf(fmaxf(acc[nt][i] + b1, 0.0f));
  }
  __syncthreads();

  // ---- M layer 2: M = h1.mw2^T + mb2, stored bf16 ----
#pragma unroll
  for (int it = 0; it < 4; ++it) {
    int f = it * 512 + t, row = f >> 4, c8 = (f & 15) * 8;
    *reinterpret_cast<bf16x8*>(&Wh[row][c8]) =
        *reinterpret_cast<const bf16x8*>(&m2b[row * 128 + c8]);
  }
  __syncthreads();
#pragma unroll
  for (int nt = 0; nt < 8; ++nt) acc[nt] = (f32x4){0.f, 0.f, 0.f, 0.f};
  mm1(Xh, Wh, me, r, q, acc);
#pragma unroll
  for (int nt = 0; nt < 8; ++nt) {
    int col = nt * 16 + r;
    float b2 = mb2[col];
#pragma unroll
    for (int i = 0; i < 4; ++i) {
      int n = n0 + me + q * 4 + i;
      if (n < NN) Mb[(size_t)n * D + col] = f2bf(acc[nt][i] + b2);
    }
  }
}

// ---------------------------------------------------------------------------
// CSR build: two-level parallel scan (scan2 folded into scan3)
// ---------------------------------------------------------------------------
constexpr int SNB = 196;   // scan blocks: 196*256 = 50176 >= NN

__global__ __launch_bounds__(256) void k_scan1(const int* __restrict__ deg,
                                               int* __restrict__ pre,
                                               int* __restrict__ bsum)
{
  __shared__ int ps[256];
  const int t = threadIdx.x, b = blockIdx.x;
  const int i = b * 256 + t;
  int v = (i < NN) ? deg[i] : 0;
  ps[t] = v;
  __syncthreads();
  for (int off = 1; off < 256; off <<= 1) {
    int u = (t >= off) ? ps[t - off] : 0;
    __syncthreads();
    ps[t] += u;
    __syncthreads();
  }
  pre[i] = ps[t] - v;               // exclusive
  if (t == 255) bsum[b] = ps[255];  // block total
}

// scan2+scan3 fused: every block redundantly scans the 196 block sums in LDS,
// picks its own base, then writes rowptr/cursor for its 256 nodes.
__global__ __launch_bounds__(256) void k_scan23(const int* __restrict__ pre,
                                                const int* __restrict__ bsum,
                                                int* __restrict__ rowptr,
                                                int* __restrict__ cursor)
{
  __shared__ int ps[256];
  const int t = threadIdx.x, b = blockIdx.x;
  int v = (t < SNB) ? bsum[t] : 0;
  ps[t] = v;
  __syncthreads();
  for (int off = 1; off < 256; off <<= 1) {
    int u = (t >= off) ? ps[t - off] : 0;
    __syncthreads();
    ps[t] += u;
    __syncthreads();
  }
  const int base = (b == 0) ? 0 : ps[b - 1];  // exclusive prefix of block b
  const int i = b * 256 + t;
  if (i < NN) {
    int vv = pre[i] + base;
    rowptr[i] = vv;
    cursor[i] = vv;
  }
  if (i == 0) rowptr[NN] = NE;
}

// ---------------------------------------------------------------------------
// K2 (frozen proven form): per-edge pass, bf16 MFMA.
// 128 edges/block, 8 waves, CSR order + XCD swizzle. LDS ~49KB -> 3 blk/CU.
// XOR swizzle; W staged in two 64-row halves in one 16KB buffer.
// ---------------------------------------------------------------------------
__global__ __launch_bounds__(512, 6) void k_edge_mfma(
    const unsigned short* __restrict__ zb, const int* __restrict__ ei,
    const int* __restrict__ etype,
    const unsigned short* __restrict__ Wcb, const float* __restrict__ tvg,
    const float* __restrict__ eb1, const float* __restrict__ ew2,
    const float* __restrict__ eb2,
    const unsigned short* __restrict__ Ab, const unsigned short* __restrict__ Bb,
    const int* __restrict__ eid, const int* __restrict__ de_perm,
    float* __restrict__ wexp_perm)
{
  __shared__ unsigned short Xb[128 * 128];   // 32KB, swizzled
  __shared__ unsigned short Wb[64 * 128];    // 16KB, swizzled, 2-phase
  __shared__ unsigned short se[128], de[128];
  __shared__ unsigned char  tyg[128];

  const int t = threadIdx.x;
  // XCD swizzle (grid 4688 % 8 == 0 -> simple bijective form)
  const int nx = gridDim.x >> 3;
  const int sb = (blockIdx.x & 7) * nx + (blockIdx.x >> 3);
  const int e0 = sb * 128;

  if (t < 128) {
    int pos = e0 + t;
    if (pos < NE) {
      int e  = eid[pos];
      se[t]  = (unsigned short)ei[e];
      de[t]  = (unsigned short)de_perm[pos];
      tyg[t] = (unsigned char)etype[e];
    } else { se[t] = 0; de[t] = 0; tyg[t] = 0; }
  }
  // stage W half 0 (global rows 0..63)
#pragma unroll
  for (int it = 0; it < 2; ++it) {
    int f = it * 512 + t, row = f >> 4, c = f & 15;
    int a = (row * 256 + c * 16) ^ ((row & 7) << 4);
    *reinterpret_cast<bf16x8*>((char*)Wb + a) =
        *reinterpret_cast<const bf16x8*>(&Wcb[row * 128 + c * 8]);
  }
  __syncthreads();

  // stage X = |zb[src]-zb[dst]| (bf16 gathers, 256B/row)
#pragma unroll
  for (int it = 0; it < 8; ++it) {
    int f = it * 512 + t, r = f >> 5, c4 = f & 31;
    ushort4 a4 = *reinterpret_cast<const ushort4*>(&zb[(size_t)se[r] * D + c4 * 4]);
    ushort4 b4 = *reinterpret_cast<const ushort4*>(&zb[(size_t)de[r] * D + c4 * 4]);
    ushort4 v;
    v.x = f2bf(fabsf(bf2f(a4.x) - bf2f(b4.x)));
    v.y = f2bf(fabsf(bf2f(a4.y) - bf2f(b4.y)));
    v.z = f2bf(fabsf(bf2f(a4.z) - bf2f(b4.z)));
    v.w = f2bf(fabsf(bf2f(a4.w) - bf2f(b4.w)));
    int a = (r * 256 + c4 * 8) ^ ((r & 7) << 4);
    *reinterpret_cast<ushort4*>((char*)Xb + a) = v;
  }
  __syncthreads();

  const int l = t & 63, q = l >> 4, r = l & 15;
  const int me = (t >> 6) * 16;

  f32x4 acc[8];
#pragma unroll
  for (int nt = 0; nt < 8; ++nt) acc[nt] = (f32x4){0.f, 0.f, 0.f, 0.f};

  // phase 0: nt 0..3
#pragma unroll
  for (int ks = 0; ks < 4; ++ks) {
    int xa = ((me + r) * 256 + ks * 64 + q * 16) ^ ((r & 7) << 4);
    bf16x8 a = *reinterpret_cast<const bf16x8*>((const char*)Xb + xa);
#pragma unroll
    for (int ntl = 0; ntl < 4; ++ntl) {
      int wrow = ntl * 16 + r;
      int wa = (wrow * 256 + ks * 64 + q * 16) ^ ((wrow & 7) << 4);
      bf16x8 b = *reinterpret_cast<const bf16x8*>((const char*)Wb + wa);
      acc[ntl] = __builtin_amdgcn_mfma_f32_16x16x32_bf16(a, b, acc[ntl], 0, 0, 0);
    }
  }
  __syncthreads();   // all waves done reading W half 0

  // stage W half 1 (global rows 64..127)
#pragma unroll
  for (int it = 0; it < 2; ++it) {
    int f = it * 512 + t, row = f >> 4, c = f & 15;
    int a = (row * 256 + c * 16) ^ ((row & 7) << 4);
    *reinterpret_cast<bf16x8*>((char*)Wb + a) =
        *reinterpret_cast<const bf16x8*>(&Wcb[(64 + row) * 128 + c * 8]);
  }
  __syncthreads();

  // phase 1: nt 4..7
#pragma unroll
  for (int ks = 0; ks < 4; ++ks) {
    int xa = ((me + r) * 256 + ks * 64 + q * 16) ^ ((r & 7) << 4);
    bf16x8 a = *reinterpret_cast<const bf16x8*>((const char*)Xb + xa);
#pragma unroll
    for (int ntl = 0; ntl < 4; ++ntl) {
      int wrow = ntl * 16 + r;
      int wa = (wrow * 256 + ks * 64 + q * 16) ^ ((wrow & 7) << 4);
      bf16x8 b = *reinterpret_cast<const bf16x8*>((const char*)Wb + wa);
      acc[4 + ntl] = __builtin_amdgcn_mfma_f32_16x16x32_bf16(a, b, acc[4 + ntl], 0, 0, 0);
    }
  }

  // epilogue: finish h, dot with ew2, reduce over 16 col-lanes
  int s[4], dd[4], ty[4];
#pragma unroll
  for (int i = 0; i < 4; ++i) {
    int el = me + q * 4 + i;
    s[i] = se[el]; dd[i] = de[el]; ty[i] = tyg[el];
  }
  float p[4] = {0.f, 0.f, 0.f, 0.f};
#pragma unroll
  for (int nt = 0; nt < 8; ++nt) {
    int col = nt * 16 + r;
    float e1  = eb1[col], w2 = ew2[col];
    float tva = tvg[col], tvb = tvg[128 + col];
#pragma unroll
    for (int i = 0; i < 4; ++i) {
      float h = acc[nt][i] + bf2f(Ab[(size_t)s[i] * D + col])
              + bf2f(Bb[(size_t)dd[i] * D + col]) + (ty[i] ? tvb : tva) + e1;
      p[i] += fmaxf(h, 0.f) * w2;
    }
  }
#pragma unroll
  for (int m = 1; m < 16; m <<= 1) {
#pragma unroll
    for (int i = 0; i < 4; ++i) p[i] += __shfl_xor(p[i], m);
  }
  if (r == 0) {
    float b2 = eb2[0];
#pragma unroll
    for (int i = 0; i < 4; ++i) {
      int pos = e0 + me + q * 4 + i;
      if (pos < NE) {
        float w = 1.0f / (1.0f + expf(-(p[i] + b2)));  // sigmoid
        wexp_perm[pos] = expf(w);                      // w in (0,1): stable
      }
    }
  }
}

// ---------------------------------------------------------------------------
// K3 v5: SINGLE-PASS per-node aggregation + alpha + residual + LayerNorm.
// acc = sum(wexp * M[dst]) accumulated WITHOUT waiting for the wexp-sum
// (the Mb gather chain starts at cycle 0); out uses acc*inv (identical math:
// sum(alpha*M) = inv * sum(wexp*M)). alpha written in a cheap post-loop
// (wexp/eid re-reads are L2-hot).
// ---------------------------------------------------------------------------
__global__ __launch_bounds__(256) void k_agg(
    const float* __restrict__ z, const float* __restrict__ wexp_perm,
    const unsigned short* __restrict__ Mb, const int* __restrict__ rowptr,
    const int* __restrict__ eid, const int* __restrict__ de_perm,
    const float* __restrict__ gamma, const float* __restrict__ beta,
    float* __restrict__ out, float* __restrict__ alpha_out)
{
  const int t = threadIdx.x;
  const int n = blockIdx.x * 4 + (t >> 6);
  const int l = t & 63;
  const int start = rowptr[n], end = rowptr[n + 1];

  float tot = 0.f;
  float2 acc = make_float2(0.f, 0.f);
  for (int base = start; base < end; base += 64) {
    int cnt = min(64, end - base);
    int dd = 0;
    float we = 0.f;
    if (l < cnt) {
      int pos = base + l;
      we = wexp_perm[pos];
      dd = de_perm[pos];
    }
    tot += we;
    int i = 0;
    for (; i + 8 <= cnt; i += 8) {
      float a[8]; int d[8]; ushort2 m[8];
#pragma unroll
      for (int j = 0; j < 8; ++j) {
        a[j] = __shfl(we, i + j);
        d[j] = __shfl(dd, i + j);
      }
#pragma unroll
      for (int j = 0; j < 8; ++j)
        m[j] = *reinterpret_cast<const ushort2*>(&Mb[(size_t)d[j] * D + l * 2]);
#pragma unroll
      for (int j = 0; j < 8; ++j) {
        acc.x = fmaf(a[j], bf2f(m[j].x), acc.x);
        acc.y = fmaf(a[j], bf2f(m[j].y), acc.y);
      }
    }
    for (; i < cnt; ++i) {
      float a = __shfl(we, i);
      int   d = __shfl(dd, i);
      ushort2 m = *reinterpret_cast<const ushort2*>(&Mb[(size_t)d * D + l * 2]);
      acc.x = fmaf(a, bf2f(m.x), acc.x);
      acc.y = fmaf(a, bf2f(m.y), acc.y);
    }
  }
#pragma unroll
  for (int off = 32; off; off >>= 1) tot += __shfl_xor(tot, off);
  const float inv = 1.0f / (tot + 1e-12f);

  // alpha pass (contiguous reads, L2-hot; scatter via eid)
  for (int base = start; base < end; base += 64) {
    int pos = base + l;
    if (pos < end) alpha_out[eid[pos]] = wexp_perm[pos] * inv;
  }

  // residual + LayerNorm (agg = acc * inv)
  float2 xz = *reinterpret_cast<const float2*>(&z[(size_t)n * D + l * 2]);
  float x0 = xz.x + acc.x * inv, x1 = xz.y + acc.y * inv;
  float s = x0 + x1;
#pragma unroll
  for (int off = 32; off; off >>= 1) s += __shfl_xor(s, off);
  const float mu = s * (1.0f / 128.0f);
  float d0 = x0 - mu, d1 = x1 - mu;
  float q = d0 * d0 + d1 * d1;
#pragma unroll
  for (int off = 32; off; off >>= 1) q += __shfl_xor(q, off);
  const float rstd = rsqrtf(q * (1.0f / 128.0f) + 1e-5f);
  float2 g = *reinterpret_cast<const float2*>(&gamma[l * 2]);
  float2 b = *reinterpret_cast<const float2*>(&beta[l * 2]);
  float2 o = make_float2(d0 * rstd * g.x + b.x, d1 * rstd * g.y + b.y);
  *reinterpret_cast<float2*>(&out[(size_t)n * D + l * 2]) = o;
}

// ---------------------------------------------------------------------------
extern "C" void kernel_launch(void* const* d_in, const int* in_sizes, int n_in,
                              void* d_out, int out_size, void* d_ws, size_t ws_size,
                              hipStream_t stream)
{
  const float* z        = (const float*)d_in[0];
  const int*   ei       = (const int*)d_in[1];   // [2,E]: src row, then dst row
  const int*   etype    = (const int*)d_in[2];
  const float* type_emb = (const float*)d_in[3];
  const float* ew1      = (const float*)d_in[4];
  const float* eb1      = (const float*)d_in[5];
  const float* ew2      = (const float*)d_in[6];
  const float* eb2      = (const float*)d_in[7];
  const float* mw1      = (const float*)d_in[8];
  const float* mb1      = (const float*)d_in[9];
  const float* mw2      = (const float*)d_in[10];
  const float* mb2      = (const float*)d_in[11];
  const float* gamma    = (const float*)d_in[12];
  const float* beta     = (const float*)d_in[13];

  // workspace (float-unit offsets):
  // Ab|Bb|Mb|zb (bf16) | wexp_perm | ints | bf16 weights | tvg | scan
  float*          ws        = (float*)d_ws;
  unsigned short* Ab        = (unsigned short*)(ws);
  unsigned short* Bb        = (unsigned short*)(ws + 3200000);
  unsigned short* Mb        = (unsigned short*)(ws + 6400000);
  unsigned short* zb        = (unsigned short*)(ws + 9600000);
  float*          wexp_perm = ws + 12800000;
  int*            deg       = (int*)(ws + 13400000);
  int*            rowptr    = deg + 50000;
  int*            cursor    = rowptr + 50004;
  int*            eid       = cursor + 50000;
  int*            de_perm   = eid + 600000;
  unsigned short* Wcb       = (unsigned short*)(ws + 14800000);
  float*          tvg       = ws + 14810000;
  unsigned short* Wab       = (unsigned short*)(ws + 14820000);
  unsigned short* Wbb       = (unsigned short*)(ws + 14830000);
  unsigned short* m1b       = (unsigned short*)(ws + 14840000);
  unsigned short* m2b       = (unsigned short*)(ws + 14850000);
  int*            pre       = (int*)(ws + 14880000);   // 50176 ints
  int*            bsum      = (int*)(ws + 14940000);   // 256

  float* out       = (float*)d_out;
  float* alpha_out = out + (size_t)NN * D;

  hipMemsetAsync(deg, 0, 50000 * sizeof(int), stream);

  k_preph<<<64 + (NE + 255) / 256, 256, 0, stream>>>(
      ew1, type_emb, mw1, mw2, ei,
      Wab, Wbb, Wcb, m1b, m2b, tvg, deg);
  k_scan1<<<SNB, 256, 0, stream>>>(deg, pre, bsum);
  k_scan23<<<SNB, 256, 0, stream>>>(pre, bsum, rowptr, cursor);
  k_nodefill<<<NB_NODE + NB_FILL, 512, 0, stream>>>(
      z, Wab, Wbb, m1b, m2b, mb1, mb2, Ab, Bb, Mb, zb,
      ei, cursor, eid, de_perm);
  k_edge_mfma<<<(NE + 127) / 128, 512, 0, stream>>>(zb, ei, etype, Wcb, tvg,
                                                    eb1, ew2, eb2, Ab, Bb,
                                                    eid, de_perm, wexp_perm);
  k_agg<<<NN / 4, 256, 0, stream>>>(z, wexp_perm, Mb, rowptr, eid, de_perm,
                                    gamma, beta, out, alpha_out);
}